// Round 10
// baseline (632.411 us; speedup 1.0000x reference)
//
#include <hip/hip_runtime.h>

// ---------------- problem constants ----------------
#define B_    64
#define TOK_  576
#define DIM_  1024
#define TXT_  512
#define NT_   1000
#define NTQ_  1024                 // kvn padded rows (zero-filled 1000..1023)
#define NTP_  1024                 // kvt padded cols / P padded cols
#define H_    24
#define BT_   (B_ * TOK_)          // 36864 rows
static constexpr float SCALE_ = 0.0441941738241592f;   // 512^-0.5

typedef __bf16 bf16x8 __attribute__((ext_vector_type(8)));
typedef float  f32x4  __attribute__((ext_vector_type(4)));

#define SBAR()  asm volatile("s_barrier" ::: "memory")
#define VMC(N)  asm volatile("s_waitcnt vmcnt(" #N ")" ::: "memory")

__device__ __forceinline__ unsigned short f2bf(float f) {
    unsigned u = __float_as_uint(f);
    u += 0x7fffu + ((u >> 16) & 1u);
    return (unsigned short)(u >> 16);
}
__device__ __forceinline__ float bf2f(unsigned short h) {
    return __uint_as_float(((unsigned)h) << 16);
}
__device__ __forceinline__ f32x4 mfma16(bf16x8 a, bf16x8 b, f32x4 c) {
    return __builtin_amdgcn_mfma_f32_16x16x32_bf16(a, b, c, 0, 0, 0);
}
__device__ __forceinline__ void unpack8(uint4 v, float* f) {
    unsigned a0 = v.x, a1 = v.y, a2 = v.z, a3 = v.w;
    f[0] = bf2f((unsigned short)(a0 & 0xffff)); f[1] = bf2f((unsigned short)(a0 >> 16));
    f[2] = bf2f((unsigned short)(a1 & 0xffff)); f[3] = bf2f((unsigned short)(a1 >> 16));
    f[4] = bf2f((unsigned short)(a2 & 0xffff)); f[5] = bf2f((unsigned short)(a2 >> 16));
    f[6] = bf2f((unsigned short)(a3 & 0xffff)); f[7] = bf2f((unsigned short)(a3 >> 16));
}
// order-preserving float->uint encoding for atomicMax over signed floats
__device__ __forceinline__ unsigned encmax(float f) {
    unsigned u = __float_as_uint(f);
    return (u & 0x80000000u) ? ~u : (u | 0x80000000u);
}
__device__ __forceinline__ float decmax(unsigned k) {
    unsigned u = (k & 0x80000000u) ? (k ^ 0x80000000u) : ~k;
    return __uint_as_float(u);
}

// async global->LDS, 16B per lane; lds base wave-uniform, lanes land at base + lane*16
typedef const __attribute__((address_space(1))) unsigned int* as1_u32p;
typedef __attribute__((address_space(3))) unsigned int* as3_u32p;
__device__ __forceinline__ void gll16(const void* g, void* l) {
    __builtin_amdgcn_global_load_lds((as1_u32p)g, (as3_u32p)l, 16, 0, 0);
}

// ---------------- merged prep: [0,256) wq | [256,272) qbias | [272,784) f2bf | [784,928) stats zero ----------------
__global__ void k_prep(const float* __restrict__ wq1, const float* __restrict__ wq2,
                       const float* __restrict__ g1, const float* __restrict__ g2,
                       const float* __restrict__ b1, const float* __restrict__ b2,
                       const float* __restrict__ wf,
                       unsigned short* __restrict__ wqt, float* __restrict__ qbias,
                       unsigned short* __restrict__ wfb, float* __restrict__ stats) {
    __shared__ float tile[64][68];
    int bx = blockIdx.x, t = threadIdx.x;
    if (bx < 256) {
        // Wq (1024x512 f32), rows pre-scaled by LN gamma -> WqT bf16 [branch][512][1024]
        int br = bx >> 7, kt = (bx >> 3) & 15, nt = bx & 7;
        const float* wq = br ? wq2 : wq1;
        const float* gg = br ? g2 : g1;
#pragma unroll
        for (int i = 0; i < 4; ++i) {
            int idx4 = t + i * 256;
            int kl = idx4 >> 4, n4 = (idx4 & 15) * 4;
            float gv = gg[kt * 64 + kl];
            float4 v = *reinterpret_cast<const float4*>(wq + (size_t)(kt * 64 + kl) * 512 + nt * 64 + n4);
            tile[kl][n4 + 0] = v.x * gv; tile[kl][n4 + 1] = v.y * gv;
            tile[kl][n4 + 2] = v.z * gv; tile[kl][n4 + 3] = v.w * gv;
        }
        __syncthreads();
#pragma unroll
        for (int i = 0; i < 4; ++i) {
            int idx4 = t + i * 256;
            int nl = idx4 >> 4, k4 = (idx4 & 15) * 4;
            ushort4 o = make_ushort4(f2bf(tile[k4 + 0][nl]), f2bf(tile[k4 + 1][nl]),
                                     f2bf(tile[k4 + 2][nl]), f2bf(tile[k4 + 3][nl]));
            *reinterpret_cast<ushort4*>(wqt + (size_t)br * 512 * 1024 + (size_t)(nt * 64 + nl) * 1024 + kt * 64 + k4) = o;
        }
    } else if (bx < 272) {
        // qbias[br][e] = sum_d beta[d] * Wq[d][e]
        int bb2 = bx - 256;
        int br = bb2 >> 3, e0 = (bb2 & 7) * 64;
        int e = e0 + (t & 63), part = t >> 6;
        const float* wq = br ? wq2 : wq1;
        const float* bb = br ? b2 : b1;
        float s = 0.f;
        for (int d = part * 256; d < part * 256 + 256; ++d) s += bb[d] * wq[(size_t)d * 512 + e];
        float* red = &tile[0][0];
        red[t] = s;
        __syncthreads();
        if (t < 64) qbias[br * 512 + e0 + t] = red[t] + red[64 + t] + red[128 + t] + red[192 + t];
    } else if (bx < 784) {
        // Wf f32 -> bf16 (131072 float4 groups over 512 blocks)
        int i = (bx - 272) * 256 + t;
        float4 v = *reinterpret_cast<const float4*>(wf + (size_t)i * 4);
        ushort4 o = make_ushort4(f2bf(v.x), f2bf(v.y), f2bf(v.z), f2bf(v.w));
        *reinterpret_cast<ushort4*>(wfb + (size_t)i * 4) = o;
    } else {
        // zero stats (denom[2BT] | avgs[BT] | maxe[BT]) = 4*BT floats = 36864 float4
        int i = (bx - 784) * 256 + t;
        *reinterpret_cast<float4*>(stats + (size_t)i * 4) = make_float4(0.f, 0.f, 0.f, 0.f);
    }
}

// ---------------- merged layernorms, wave-per-row, lane-contiguous loads ----------------
__global__ __launch_bounds__(512, 4) void k_lnorm(const float* __restrict__ tf,
                                                  const float* __restrict__ g,
                                                  const float* __restrict__ bta,
                                                  const float* __restrict__ x,
                                                  unsigned short* __restrict__ kvn,
                                                  unsigned short* __restrict__ xn) {
    int bid = blockIdx.x;
    int l = threadIdx.x & 63;
    if (bid < 8192) {
        int trow = bid * 8 + (threadIdx.x >> 6);     // tf-order: n*64 + b
        int n = trow >> 6, b = trow & 63;
        unsigned short* dst = kvn + ((size_t)b * NTQ_ + n) * TXT_;
        if (n >= NT_) {
            *reinterpret_cast<ushort4*>(dst + l * 4) = make_ushort4(0, 0, 0, 0);
            *reinterpret_cast<ushort4*>(dst + 256 + l * 4) = make_ushort4(0, 0, 0, 0);
            return;
        }
        const float* src = tf + (size_t)trow * TXT_;
        float4 v0 = *reinterpret_cast<const float4*>(src + l * 4);
        float4 v1 = *reinterpret_cast<const float4*>(src + 256 + l * 4);
        float s  = v0.x + v0.y + v0.z + v0.w + v1.x + v1.y + v1.z + v1.w;
        float ss = v0.x * v0.x + v0.y * v0.y + v0.z * v0.z + v0.w * v0.w
                 + v1.x * v1.x + v1.y * v1.y + v1.z * v1.z + v1.w * v1.w;
#pragma unroll
        for (int d = 1; d < 64; d <<= 1) { s += __shfl_xor(s, d); ss += __shfl_xor(ss, d); }
        float m = s * (1.f / TXT_);
        float rs = rsqrtf(ss * (1.f / TXT_) - m * m + 1e-5f);
        float4 g0 = *reinterpret_cast<const float4*>(g + l * 4);
        float4 g1 = *reinterpret_cast<const float4*>(g + 256 + l * 4);
        float4 b0 = *reinterpret_cast<const float4*>(bta + l * 4);
        float4 b1 = *reinterpret_cast<const float4*>(bta + 256 + l * 4);
        ushort4 o0 = make_ushort4(f2bf((v0.x - m) * rs * g0.x + b0.x),
                                  f2bf((v0.y - m) * rs * g0.y + b0.y),
                                  f2bf((v0.z - m) * rs * g0.z + b0.z),
                                  f2bf((v0.w - m) * rs * g0.w + b0.w));
        ushort4 o1 = make_ushort4(f2bf((v1.x - m) * rs * g1.x + b1.x),
                                  f2bf((v1.y - m) * rs * g1.y + b1.y),
                                  f2bf((v1.z - m) * rs * g1.z + b1.z),
                                  f2bf((v1.w - m) * rs * g1.w + b1.w));
        *reinterpret_cast<ushort4*>(dst + l * 4) = o0;
        *reinterpret_cast<ushort4*>(dst + 256 + l * 4) = o1;
    } else {
        int gr = 64 + (bid - 8192) * 8 + (threadIdx.x >> 6);
        int b = gr & 63, tk = (gr >> 6) - 1;
        const float* src = x + (size_t)gr * DIM_;
        float4 v[4];
#pragma unroll
        for (int j = 0; j < 4; ++j) v[j] = *reinterpret_cast<const float4*>(src + j * 256 + l * 4);
        float s = 0.f, ss = 0.f;
#pragma unroll
        for (int j = 0; j < 4; ++j) {
            s += v[j].x + v[j].y + v[j].z + v[j].w;
            ss += v[j].x * v[j].x + v[j].y * v[j].y + v[j].z * v[j].z + v[j].w * v[j].w;
        }
#pragma unroll
        for (int d = 1; d < 64; d <<= 1) { s += __shfl_xor(s, d); ss += __shfl_xor(ss, d); }
        float m = s * (1.f / DIM_);
        float rs = rsqrtf(ss * (1.f / DIM_) - m * m + 1e-5f);
        unsigned short* dst = xn + ((size_t)b * TOK_ + tk) * DIM_;
#pragma unroll
        for (int j = 0; j < 4; ++j) {
            ushort4 o = make_ushort4(f2bf((v[j].x - m) * rs), f2bf((v[j].y - m) * rs),
                                     f2bf((v[j].z - m) * rs), f2bf((v[j].w - m) * rs));
            *reinterpret_cast<ushort4*>(dst + j * 256 + l * 4) = o;
        }
    }
}

// ---------------- kv transpose:  kvn [b][n][e] -> kvt [b][e][n_pad1024] ----------------
__global__ void k_kvt(const unsigned short* __restrict__ kvn, unsigned short* __restrict__ kvt) {
    __shared__ unsigned short tile[64][68];
    int bx = blockIdx.x;
    int b = bx >> 7, rem = bx & 127, et = rem >> 4, nt = rem & 15;
    int t = threadIdx.x;
#pragma unroll
    for (int i = 0; i < 4; ++i) {
        int idx4 = t + i * 256;
        int nl = idx4 >> 4, e4 = (idx4 & 15) * 4;
        int ng = nt * 64 + nl;
        ushort4 v = make_ushort4(0, 0, 0, 0);
        if (ng < NT_) v = *reinterpret_cast<const ushort4*>(kvn + ((size_t)b * NTQ_ + ng) * TXT_ + et * 64 + e4);
        tile[nl][e4 + 0] = v.x; tile[nl][e4 + 1] = v.y; tile[nl][e4 + 2] = v.z; tile[nl][e4 + 3] = v.w;
    }
    __syncthreads();
#pragma unroll
    for (int i = 0; i < 4; ++i) {
        int idx4 = t + i * 256;
        int el = idx4 >> 4, n4 = (idx4 & 15) * 4;
        ushort4 o = make_ushort4(tile[n4 + 0][el], tile[n4 + 1][el], tile[n4 + 2][el], tile[n4 + 3][el]);
        *reinterpret_cast<ushort4*>(kvt + ((size_t)b * TXT_ + et * 64 + el) * NTP_ + nt * 64 + n4) = o;
    }
}

// ================= 8-phase 256x256 GEMM (T2+T3+T4+T5 template) for q-projection =================
// One GEMM: M=36864 (xn rows), N=1024 (branch-concat wqt rows), K=1024.
// 8 waves (2M x 4N), per-wave C 128x64. LDS: 2 dbuf x {A,B} x {kh0,kh1} planes of [256 rows][32k].
// Staging: global_load_lds, linear LDS, PRE-SWIZZLED source granule gs = (l&3) ^ ((l>>3)&3).
// Reads: ds_read_b128 at granule lg ^ ((row>>1)&3)  -> <=2-way bank aliasing.
// Counted vmcnt: stages [A0,B0,A1,B1]/K-tile; waits vmcnt(6) at phases 1 and 3 (never 0 until drain).
__global__ __launch_bounds__(512, 2) void k_qgemm8(const unsigned short* __restrict__ xn,
                                                   const unsigned short* __restrict__ wqt,
                                                   const float* __restrict__ qbias,
                                                   unsigned short* __restrict__ qb) {
    __shared__ unsigned short lds[8][8192];      // 128 KB: plane = buf*4 + isB*2 + kh
    int bid = blockIdx.x;                        // 576 = 144 bm x 4 bn
    int vb = (bid & 7) * 72 + (bid >> 3);        // bijective XCD swizzle (576 = 8*72)
    int bn = vb & 3, bm = vb >> 2;
    const unsigned short* Ab = xn + (size_t)bm * 256 * DIM_;
    const unsigned short* Bb = wqt + (size_t)bn * 256 * DIM_;
    const int tid = threadIdx.x, w = tid >> 6, l = tid & 63;
    const int l16 = l & 15, lg = l >> 4;
    const int wm = w >> 2, wn = w & 3;           // 2M x 4N waves
    const int srow = l >> 2;                     // staging: lane's row within 16-row group
    const int sgs = (l & 3) ^ ((srow >> 1) & 3); // pre-swizzled source granule

    // stage one K-half plane (256 rows x 32k) : 2 x gll16 per thread
    auto STAGE = [&](int plane, const unsigned short* src, int kt, int kh) {
#pragma unroll
        for (int i = 0; i < 2; ++i) {
            int row = i * 128 + w * 16 + srow;
            gll16(src + (size_t)row * DIM_ + kt * 64 + kh * 32 + sgs * 8,
                  &lds[plane][(i * 128 + w * 16) * 32]);
        }
    };
    auto RD = [&](int plane, int row) -> bf16x8 {
        int gg = lg ^ ((row >> 1) & 3);
        return *reinterpret_cast<const bf16x8*>(&lds[plane][row * 32 + gg * 8]);
    };

    const f32x4 fz = {0.f, 0.f, 0.f, 0.f};
    f32x4 acc[8][4];
#pragma unroll
    for (int mt = 0; mt < 8; ++mt)
#pragma unroll
        for (int nt = 0; nt < 4; ++nt) acc[mt][nt] = fz;

    const int NK = DIM_ / 64;                    // 16 K-tiles
    // prologue: stage kt=0 in FIFO order [A-kh0, B-kh0, A-kh1, B-kh1]
    STAGE(0, Ab, 0, 0); STAGE(2, Bb, 0, 0); STAGE(1, Ab, 0, 1); STAGE(3, Bb, 0, 1);

    bf16x8 af_[4], bf_[4];
    for (int kt = 0; kt < NK; ++kt) {
        const int pb = (kt & 1) * 4, nb = pb ^ 4;
        const bool pf = (kt + 1 < NK);
        // ---- phase 1: kk=0, mt 0..3 (needs A-kh0, B-kh0 of kt)
        if (pf) { STAGE(nb + 0, Ab, kt + 1, 0); VMC(6); } else { VMC(4); }
        SBAR();
#pragma unroll
        for (int nt = 0; nt < 4; ++nt) bf_[nt] = RD(pb + 2, wn * 64 + nt * 16 + l16);
#pragma unroll
        for (int mt = 0; mt < 4; ++mt) af_[mt] = RD(pb + 0, wm * 128 + mt * 16 + l16);
        __builtin_amdgcn_s_setprio(1);
#pragma unroll
        for (int mt = 0; mt < 4; ++mt)
#pragma unroll
            for (int nt = 0; nt < 4; ++nt) acc[mt][nt] = mfma16(af_[mt], bf_[nt], acc[mt][nt]);
        __builtin_amdgcn_s_setprio(0);
        SBAR();
        // ---- phase 2: kk=0, mt 4..7 (B-frags reused in regs)
        if (pf) STAGE(nb + 2, Bb, kt + 1, 0);
        SBAR();
#pragma unroll
        for (int mt = 0; mt < 4; ++mt) af_[mt] = RD(pb + 0, wm * 128 + 64 + mt * 16 + l16);
        __builtin_amdgcn_s_setprio(1);
#pragma unroll
        for (int mt = 0; mt < 4; ++mt)
#pragma unroll
            for (int nt = 0; nt < 4; ++nt) acc[4 + mt][nt] = mfma16(af_[mt], bf_[nt], acc[4 + mt][nt]);
        __builtin_amdgcn_s_setprio(0);
        SBAR();
        // ---- phase 3: kk=1, mt 0..3 (needs A-kh1, B-kh1 of kt)
        if (pf) { STAGE(nb + 1, Ab, kt + 1, 1); VMC(6); } else { VMC(0); }
        SBAR();
#pragma unroll
        for (int nt = 0; nt < 4; ++nt) bf_[nt] = RD(pb + 3, wn * 64 + nt * 16 + l16);
#pragma unroll
        for (int mt = 0; mt < 4; ++mt) af_[mt] = RD(pb + 1, wm * 128 + mt * 16 + l16);
        __builtin_amdgcn_s_setprio(1);
#pragma unroll
        for (int mt = 0; mt < 4; ++mt)
#pragma unroll
            for (int nt = 0; nt < 4; ++nt) acc[mt][nt] = mfma16(af_[mt], bf_[nt], acc[mt][nt]);
        __builtin_amdgcn_s_setprio(0);
        SBAR();
        // ---- phase 4: kk=1, mt 4..7
        if (pf) STAGE(nb + 3, Bb, kt + 1, 1);
        SBAR();
#pragma unroll
        for (int mt = 0; mt < 4; ++mt) af_[mt] = RD(pb + 1, wm * 128 + 64 + mt * 16 + l16);
        __builtin_amdgcn_s_setprio(1);
#pragma unroll
        for (int mt = 0; mt < 4; ++mt)
#pragma unroll
            for (int nt = 0; nt < 4; ++nt) acc[4 + mt][nt] = mfma16(af_[mt], bf_[nt], acc[4 + mt][nt]);
        __builtin_amdgcn_s_setprio(0);
        SBAR();
    }
    // ---- epilogue: + bias, * SCALE, split branch by column
#pragma unroll
    for (int mt = 0; mt < 8; ++mt)
#pragma unroll
        for (int nt = 0; nt < 4; ++nt) {
            int colg = bn * 256 + wn * 64 + nt * 16 + l16;
            int br = colg >> 9, col = colg & 511;
            float bv = qbias[colg];
            unsigned short* C = qb + (size_t)br * BT_ * TXT_;
#pragma unroll
            for (int r = 0; r < 4; ++r) {
                int row = bm * 256 + wm * 128 + mt * 16 + lg * 4 + r;
                C[(size_t)row * TXT_ + col] = f2bf((acc[mt][nt][r] + bv) * SCALE_);
            }
        }
}

// ---------------- 128x128xK bf16 GEMM mainloop, global_load_lds staging (m97 structure) ----------------
__device__ __forceinline__ void gemm_loop_gll(const unsigned short* __restrict__ A,
                                              const unsigned short* __restrict__ Bp,
                                              int K, unsigned short* a_lds, unsigned short* b_lds,
                                              int tid, f32x4 acc[4][4]) {
    const int l = tid & 63, w = tid >> 6;
    const int l16 = l & 15, lg = l >> 4;
    const int wm = w & 1, wn = w >> 1;
    const f32x4 fz = {0.f, 0.f, 0.f, 0.f};
#pragma unroll
    for (int mt = 0; mt < 4; ++mt)
#pragma unroll
        for (int nt = 0; nt < 4; ++nt) acc[mt][nt] = fz;
    const int lrow = l >> 3;
    const int k8g = (l & 7) ^ lrow;
    const int nk = K >> 6;
    for (int kt = 0; kt < nk; ++kt) {
#pragma unroll
        for (int i = 0; i < 4; ++i) {
            int row = i * 32 + w * 8 + lrow;
            gll16(A + (size_t)row * K + kt * 64 + k8g * 8, &a_lds[(i * 256 + w * 64) * 8]);
        }
#pragma unroll
        for (int i = 0; i < 4; ++i) {
            int row = i * 32 + w * 8 + lrow;
            gll16(Bp + (size_t)row * K + kt * 64 + k8g * 8, &b_lds[(i * 256 + w * 64) * 8]);
        }
        __syncthreads();
#pragma unroll
        for (int kk = 0; kk < 2; ++kk) {
            bf16x8 af[4], bff[4];
#pragma unroll
            for (int mt = 0; mt < 4; ++mt) {
                int row = wm * 64 + mt * 16 + l16;
                int gs = (kk * 4 + lg) ^ (row & 7);
                af[mt] = *reinterpret_cast<const bf16x8*>(a_lds + row * 64 + gs * 8);
            }
#pragma unroll
            for (int nt = 0; nt < 4; ++nt) {
                int row = wn * 64 + nt * 16 + l16;
                int gs = (kk * 4 + lg) ^ (row & 7);
                bff[nt] = *reinterpret_cast<const bf16x8*>(b_lds + row * 64 + gs * 8);
            }
#pragma unroll
            for (int mt = 0; mt < 4; ++mt)
#pragma unroll
                for (int nt = 0; nt < 4; ++nt)
                    acc[mt][nt] = mfma16(af[mt], bff[nt], acc[mt][nt]);
        }
        __syncthreads();
    }
}

// ---------------- 96x128xK variant (M-tile 96 keeps tiles inside one b: 576 = 6*96) ----------------
__device__ __forceinline__ void gemm_loop96(const unsigned short* __restrict__ A,
                                            const unsigned short* __restrict__ Bp,
                                            int K, unsigned short* a_lds, unsigned short* b_lds,
                                            int tid, f32x4 acc[3][4]) {
    const int l = tid & 63, w = tid >> 6;
    const int l16 = l & 15, lg = l >> 4;
    const int wm = w & 1, wn = w >> 1;
    const f32x4 fz = {0.f, 0.f, 0.f, 0.f};
#pragma unroll
    for (int mt = 0; mt < 3; ++mt)
#pragma unroll
        for (int nt = 0; nt < 4; ++nt) acc[mt][nt] = fz;
    const int lrow = l >> 3;
    const int k8g = (l & 7) ^ lrow;
    const int nk = K >> 6;
    for (int kt = 0; kt < nk; ++kt) {
#pragma unroll
        for (int i = 0; i < 3; ++i) {
            int row = i * 32 + w * 8 + lrow;
            gll16(A + (size_t)row * K + kt * 64 + k8g * 8, &a_lds[(i * 256 + w * 64) * 8]);
        }
#pragma unroll
        for (int i = 0; i < 4; ++i) {
            int row = i * 32 + w * 8 + lrow;
            gll16(Bp + (size_t)row * K + kt * 64 + k8g * 8, &b_lds[(i * 256 + w * 64) * 8]);
        }
        __syncthreads();
#pragma unroll
        for (int kk = 0; kk < 2; ++kk) {
            bf16x8 af[3], bff[4];
#pragma unroll
            for (int mt = 0; mt < 3; ++mt) {
                int row = wm * 48 + mt * 16 + l16;
                int gs = (kk * 4 + lg) ^ (row & 7);
                af[mt] = *reinterpret_cast<const bf16x8*>(a_lds + row * 64 + gs * 8);
            }
#pragma unroll
            for (int nt = 0; nt < 4; ++nt) {
                int row = wn * 64 + nt * 16 + l16;
                int gs = (kk * 4 + lg) ^ (row & 7);
                bff[nt] = *reinterpret_cast<const bf16x8*>(b_lds + row * 64 + gs * 8);
            }
#pragma unroll
            for (int mt = 0; mt < 3; ++mt)
#pragma unroll
                for (int nt = 0; nt < 4; ++nt)
                    acc[mt][nt] = mfma16(af[mt], bff[nt], acc[mt][nt]);
        }
        __syncthreads();
    }
}

// score GEMM: P = exp(q @ kvn^T) per branch, + row-sum atomics into denom
__global__ __launch_bounds__(256, 4) void k_score(const unsigned short* __restrict__ qbuf,
                                                  const unsigned short* __restrict__ kvn,
                                                  unsigned short* __restrict__ P,
                                                  float* __restrict__ denom, int br) {
    int bid = blockIdx.x;                        // 3072 = 64b x 6mt x 8nt
    int vb = (bid & 7) * 384 + (bid >> 3);
    int tile = vb % 48, b = vb / 48;
    int mt = tile >> 3, nt = tile & 7;
    const unsigned short* A = qbuf + ((size_t)br * BT_ + (size_t)b * TOK_ + mt * 96) * TXT_;
    const unsigned short* Bp = kvn + (size_t)b * NTQ_ * TXT_ + (size_t)nt * 128 * TXT_;
    __shared__ unsigned short a_lds[96 * 64];
    __shared__ unsigned short b_lds[128 * 64];
    f32x4 acc[3][4];
    gemm_loop96(A, Bp, TXT_, a_lds, b_lds, threadIdx.x, acc);
    const int l = threadIdx.x & 63, w = threadIdx.x >> 6;
    const int l16 = l & 15, lg = l >> 4, wm = w & 1, wn = w >> 1;
    float* dn = denom + (size_t)br * BT_;
#pragma unroll
    for (int mt2 = 0; mt2 < 3; ++mt2)
#pragma unroll
        for (int r = 0; r < 4; ++r) {
            int row = b * TOK_ + mt * 96 + wm * 48 + mt2 * 16 + lg * 4 + r;
            float s = 0.f;
#pragma unroll
            for (int nt2 = 0; nt2 < 4; ++nt2) {
                int col = nt * 128 + wn * 64 + nt2 * 16 + l16;
                float p = (col < NT_) ? __expf(acc[mt2][nt2][r]) : 0.f;
                s += p;
                P[(size_t)row * NTP_ + col] = f2bf(p);
            }
#pragma unroll
            for (int d = 1; d < 16; d <<= 1) s += __shfl_xor(s, d);
            if (l16 == 0) atomicAdd(&dn[row], s);
        }
}

// PV GEMM: O = (P @ kvt^T) / denom -> bf16; fused per-row sum (br0) / max (br1) atomics
__global__ __launch_bounds__(256, 4) void k_pv(const unsigned short* __restrict__ P,
                                               const unsigned short* __restrict__ kvt,
                                               const float* __restrict__ denom,
                                               unsigned short* __restrict__ ob,
                                               float* __restrict__ avgs,
                                               unsigned* __restrict__ maxe, int br) {
    int bid = blockIdx.x;                        // 1536 = 64b x 6mt x 4nt
    int vb = (bid & 7) * 192 + (bid >> 3);
    int tile = vb % 24, b = vb / 24;
    int mt = tile >> 2, nt = tile & 3;
    const unsigned short* A = P + ((size_t)b * TOK_ + mt * 96) * NTP_;
    const unsigned short* Bp = kvt + (size_t)b * TXT_ * NTP_ + (size_t)nt * 128 * NTP_;
    __shared__ unsigned short a_lds[96 * 64];
    __shared__ unsigned short b_lds[128 * 64];
    f32x4 acc[3][4];
    gemm_loop96(A, Bp, NTP_, a_lds, b_lds, threadIdx.x, acc);
    const int l = threadIdx.x & 63, w = threadIdx.x >> 6;
    const int l16 = l & 15, lg = l >> 4, wm = w & 1, wn = w >> 1;
    const float* dn = denom + (size_t)br * BT_;
#pragma unroll
    for (int mt2 = 0; mt2 < 3; ++mt2)
#pragma unroll
        for (int r = 0; r < 4; ++r) {
            int row = b * TOK_ + mt * 96 + wm * 48 + mt2 * 16 + lg * 4 + r;
            float inv = 1.f / dn[row];
            unsigned short* dst = ob + ((size_t)br * BT_ + row) * TXT_;
            float sum = 0.f, mx = -1e30f;
#pragma unroll
            for (int nt2 = 0; nt2 < 4; ++nt2) {
                int col = nt * 128 + wn * 64 + nt2 * 16 + l16;
                float o = acc[mt2][nt2][r] * inv;
                dst[col] = f2bf(o);
                sum += o;
                mx = fmaxf(mx, o);
            }
#pragma unroll
            for (int d = 1; d < 16; d <<= 1) {
                sum += __shfl_xor(sum, d);
                mx = fmaxf(mx, __shfl_xor(mx, d));
            }
            if (l16 == 0) {
                if (br == 0) atomicAdd(&avgs[row], sum);
                else         atomicMax(&maxe[row], encmax(mx));
            }
        }
}

// final GEMM: y = xse (36864x512) @ Wf^T (1024x512) -> fp32 scattered into out layout
__global__ __launch_bounds__(256, 4) void k_fgemm(const unsigned short* __restrict__ xse,
                                                  const unsigned short* __restrict__ wfb,
                                                  float* __restrict__ out) {
    int bid = blockIdx.x;                        // 2304 = 8bn x 288bm
    int vb = (bid & 7) * 288 + (bid >> 3);
    int bn = vb & 7, bm = vb >> 3;
    const unsigned short* A = xse + (size_t)bm * 128 * TXT_;
    const unsigned short* Bp = wfb + (size_t)bn * 128 * TXT_;
    __shared__ unsigned short a_lds[128 * 64];
    __shared__ unsigned short b_lds[128 * 64];
    f32x4 acc[4][4];
    gemm_loop_gll(A, Bp, TXT_, a_lds, b_lds, threadIdx.x, acc);
    const int l = threadIdx.x & 63, w = threadIdx.x >> 6;
    const int l16 = l & 15, lg = l >> 4, wm = w & 1, wn = w >> 1;
#pragma unroll
    for (int mt = 0; mt < 4; ++mt)
#pragma unroll
        for (int r = 0; r < 4; ++r) {
            int rowg = bm * 128 + wm * 64 + mt * 16 + lg * 4 + r;
            int b = rowg / TOK_, tk = rowg - b * TOK_;
            float* dst = out + ((size_t)(tk + 1) * B_ + b) * DIM_;
#pragma unroll
            for (int nt = 0; nt < 4; ++nt) {
                int col = bn * 128 + wn * 64 + nt * 16 + l16;
                dst[col] = acc[mt][nt][r];
            }
        }
}

// ---------------- x_se = o1*g1 + o2*g2 -> bf16, with gate conv fused (lane 0 per row) ----------------
__global__ void k_xse(const unsigned short* __restrict__ o1, const unsigned short* __restrict__ o2,
                      const float* __restrict__ avgs, const unsigned* __restrict__ maxe,
                      const float* __restrict__ cdw, unsigned short* __restrict__ xse) {
    int idx8 = blockIdx.x * 256 + threadIdx.x;    // < 36864*64
    int bt = idx8 >> 6, e8 = threadIdx.x & 63;
    float gg1 = 0.f, gg2 = 0.f;
    if (e8 == 0) {
        int b = bt / TOK_, hw = bt - b * TOK_, h = hw / H_, ww = hw - h * H_;
        float a1 = 0.f, a2 = 0.f;
#pragma unroll
        for (int ky = 0; ky < 3; ++ky)
#pragma unroll
            for (int kx = 0; kx < 3; ++kx) {
                int hh = h + ky - 1, wx = ww + kx - 1;
                if (hh >= 0 && hh < H_ && wx >= 0 && wx < H_) {
                    float wv = cdw[ky * 3 + kx];
                    int s = b * TOK_ + hh * H_ + wx;
                    a1 += wv * avgs[s] * (1.f / TXT_);
                    a2 += wv * decmax(maxe[s]);
                }
            }
        gg1 = 1.f / (1.f + __expf(-a1));
        gg2 = 1.f / (1.f + __expf(-a2));
    }
    gg1 = __shfl(gg1, 0);
    gg2 = __shfl(gg2, 0);
    float f1[8], f2[8];
    unpack8(*reinterpret_cast<const uint4*>(o1 + (size_t)bt * TXT_ + e8 * 8), f1);
    unpack8(*reinterpret_cast<const uint4*>(o2 + (size_t)bt * TXT_ + e8 * 8), f2);
    unsigned r[4];
#pragma unroll
    for (int j = 0; j < 4; ++j) {
        unsigned lo = f2bf(f1[2 * j] * gg1 + f2[2 * j] * gg2);
        unsigned hi = f2bf(f1[2 * j + 1] * gg1 + f2[2 * j + 1] * gg2);
        r[j] = lo | (hi << 16);
    }
    uint4 o = make_uint4(r[0], r[1], r[2], r[3]);
    *reinterpret_cast<uint4*>(xse + (size_t)bt * TXT_ + e8 * 8) = o;
}

// ---------------- launcher ----------------
extern "C" void kernel_launch(void* const* d_in, const int* in_sizes, int n_in,
                              void* d_out, int out_size, void* d_ws, size_t ws_size,
                              hipStream_t stream) {
    (void)in_sizes; (void)n_in; (void)out_size; (void)ws_size;
    const float* x    = (const float*)d_in[0];
    const float* tf   = (const float*)d_in[1];
    const float* lq1g = (const float*)d_in[2];
    const float* lq1b = (const float*)d_in[3];
    const float* lq2g = (const float*)d_in[4];
    const float* lq2b = (const float*)d_in[5];
    const float* lkvg = (const float*)d_in[6];
    const float* lkvb = (const float*)d_in[7];
    const float* wq1  = (const float*)d_in[8];
    const float* wq2  = (const float*)d_in[9];
    const float* cdw  = (const float*)d_in[10];
    const float* wf   = (const float*)d_in[11];
    float* out = (float*)d_out;

    char* ws = (char*)d_ws;
    size_t off = 0;
    auto carve = [&](size_t bytes) { char* p = ws + off; off += (bytes + 255) & ~(size_t)255; return p; };
    unsigned short* kvn  = (unsigned short*)carve((size_t)B_ * NTQ_ * TXT_ * 2);       // 67.1 MB
    unsigned short* kvt  = (unsigned short*)carve((size_t)B_ * TXT_ * NTP_ * 2);       // 67.1 MB
    unsigned short* wqt  = (unsigned short*)carve((size_t)2 * 512 * 1024 * 2);         // 2 MB
    unsigned short* wfb  = (unsigned short*)carve((size_t)1024 * 512 * 2);             // 1 MB
    float* qbias = (float*)carve((size_t)2 * 512 * 4);
    float* stats = (float*)carve((size_t)4 * BT_ * 4);                                 // denom[2BT] | avgs[BT] | maxe[BT]
    float* denom = stats;
    float* avgs  = stats + 2 * BT_;
    unsigned* maxe = (unsigned*)(stats + 3 * BT_);
    unsigned short* xn   = (unsigned short*)carve((size_t)BT_ * DIM_ * 2);             // 75.5 MB
    unsigned short* qbuf = (unsigned short*)carve((size_t)2 * BT_ * TXT_ * 2);         // 75.5 MB
    unsigned short* ob   = (unsigned short*)carve((size_t)2 * BT_ * TXT_ * 2);         // 75.5 MB
    unsigned short* Pm   = xn;     // P (36864x1024 bf16, per branch): xn dead after k_qgemm8
    unsigned short* xse  = qbuf;   // safe: qbuf dead after last k_score

    // row 0 of output = x_cls
    hipMemcpyAsync(out, x, (size_t)B_ * DIM_ * sizeof(float), hipMemcpyDeviceToDevice, stream);

    k_prep<<<928, 256, 0, stream>>>(wq1, wq2, lq1g, lq2g, lq1b, lq2b, wf, wqt, qbias, wfb, stats);
    k_lnorm<<<12800, 512, 0, stream>>>(tf, lkvg, lkvb, x, kvn, xn);
    k_kvt<<<8192, 256, 0, stream>>>(kvn, kvt);
    k_qgemm8<<<576, 512, 0, stream>>>(xn, wqt, qbias, qbuf);
    // branch 0
    k_score<<<3072, 256, 0, stream>>>(qbuf, kvn, Pm, denom, 0);
    k_pv<<<1536, 256, 0, stream>>>(Pm, kvt, denom, ob, avgs, maxe, 0);
    // branch 1 (P buffer reused; stream-ordered)
    k_score<<<3072, 256, 0, stream>>>(qbuf, kvn, Pm, denom, 1);
    k_pv<<<1536, 256, 0, stream>>>(Pm, kvt, denom, ob, avgs, maxe, 1);
    k_xse<<<9216, 256, 0, stream>>>(ob, ob + (size_t)BT_ * TXT_, avgs, maxe, cdw, xse);
    k_fgemm<<<2304, 256, 0, stream>>>(xse, wfb, out);
}

// Round 11
// 614.197 us; speedup vs baseline: 1.0297x; 1.0297x over previous
//
#include <hip/hip_runtime.h>

// ---------------- problem constants ----------------
#define B_    64
#define TOK_  576
#define DIM_  1024
#define TXT_  512
#define NT_   1000
#define NTQ_  1024                 // kvn padded rows (zero-filled 1000..1023)
#define NTP_  1024                 // kvt padded cols / P padded cols
#define H_    24
#define BT_   (B_ * TOK_)          // 36864 rows
static constexpr float SCALE_ = 0.0441941738241592f;   // 512^-0.5

typedef __bf16 bf16x8 __attribute__((ext_vector_type(8)));
typedef float  f32x4  __attribute__((ext_vector_type(4)));

__device__ __forceinline__ unsigned short f2bf(float f) {
    unsigned u = __float_as_uint(f);
    u += 0x7fffu + ((u >> 16) & 1u);
    return (unsigned short)(u >> 16);
}
__device__ __forceinline__ float bf2f(unsigned short h) {
    return __uint_as_float(((unsigned)h) << 16);
}
__device__ __forceinline__ f32x4 mfma16(bf16x8 a, bf16x8 b, f32x4 c) {
    return __builtin_amdgcn_mfma_f32_16x16x32_bf16(a, b, c, 0, 0, 0);
}
__device__ __forceinline__ void unpack8(uint4 v, float* f) {
    unsigned a0 = v.x, a1 = v.y, a2 = v.z, a3 = v.w;
    f[0] = bf2f((unsigned short)(a0 & 0xffff)); f[1] = bf2f((unsigned short)(a0 >> 16));
    f[2] = bf2f((unsigned short)(a1 & 0xffff)); f[3] = bf2f((unsigned short)(a1 >> 16));
    f[4] = bf2f((unsigned short)(a2 & 0xffff)); f[5] = bf2f((unsigned short)(a2 >> 16));
    f[6] = bf2f((unsigned short)(a3 & 0xffff)); f[7] = bf2f((unsigned short)(a3 >> 16));
}
// order-preserving float->uint encoding for atomicMax over signed floats
__device__ __forceinline__ unsigned encmax(float f) {
    unsigned u = __float_as_uint(f);
    return (u & 0x80000000u) ? ~u : (u | 0x80000000u);
}
__device__ __forceinline__ float decmax(unsigned k) {
    unsigned u = (k & 0x80000000u) ? (k ^ 0x80000000u) : ~k;
    return __uint_as_float(u);
}

// async global->LDS, 16B per lane; lds base wave-uniform, lanes land at base + lane*16
typedef const __attribute__((address_space(1))) unsigned int* as1_u32p;
typedef __attribute__((address_space(3))) unsigned int* as3_u32p;
__device__ __forceinline__ void gll16(const void* g, void* l) {
    __builtin_amdgcn_global_load_lds((as1_u32p)g, (as3_u32p)l, 16, 0, 0);
}

// ---------------- merged prep: [0,256) wq | [256,272) qbias | [272,784) f2bf | [784,928) stats zero ----------------
__global__ void k_prep(const float* __restrict__ wq1, const float* __restrict__ wq2,
                       const float* __restrict__ g1, const float* __restrict__ g2,
                       const float* __restrict__ b1, const float* __restrict__ b2,
                       const float* __restrict__ wf,
                       unsigned short* __restrict__ wqt, float* __restrict__ qbias,
                       unsigned short* __restrict__ wfb, float* __restrict__ stats) {
    __shared__ float tile[64][68];
    int bx = blockIdx.x, t = threadIdx.x;
    if (bx < 256) {
        // Wq (1024x512 f32), rows pre-scaled by LN gamma -> WqT bf16 [branch][512][1024]
        int br = bx >> 7, kt = (bx >> 3) & 15, nt = bx & 7;
        const float* wq = br ? wq2 : wq1;
        const float* gg = br ? g2 : g1;
#pragma unroll
        for (int i = 0; i < 4; ++i) {
            int idx4 = t + i * 256;
            int kl = idx4 >> 4, n4 = (idx4 & 15) * 4;
            float gv = gg[kt * 64 + kl];
            float4 v = *reinterpret_cast<const float4*>(wq + (size_t)(kt * 64 + kl) * 512 + nt * 64 + n4);
            tile[kl][n4 + 0] = v.x * gv; tile[kl][n4 + 1] = v.y * gv;
            tile[kl][n4 + 2] = v.z * gv; tile[kl][n4 + 3] = v.w * gv;
        }
        __syncthreads();
#pragma unroll
        for (int i = 0; i < 4; ++i) {
            int idx4 = t + i * 256;
            int nl = idx4 >> 4, k4 = (idx4 & 15) * 4;
            ushort4 o = make_ushort4(f2bf(tile[k4 + 0][nl]), f2bf(tile[k4 + 1][nl]),
                                     f2bf(tile[k4 + 2][nl]), f2bf(tile[k4 + 3][nl]));
            *reinterpret_cast<ushort4*>(wqt + (size_t)br * 512 * 1024 + (size_t)(nt * 64 + nl) * 1024 + kt * 64 + k4) = o;
        }
    } else if (bx < 272) {
        // qbias[br][e] = sum_d beta[d] * Wq[d][e]
        int bb2 = bx - 256;
        int br = bb2 >> 3, e0 = (bb2 & 7) * 64;
        int e = e0 + (t & 63), part = t >> 6;
        const float* wq = br ? wq2 : wq1;
        const float* bb = br ? b2 : b1;
        float s = 0.f;
        for (int d = part * 256; d < part * 256 + 256; ++d) s += bb[d] * wq[(size_t)d * 512 + e];
        float* red = &tile[0][0];
        red[t] = s;
        __syncthreads();
        if (t < 64) qbias[br * 512 + e0 + t] = red[t] + red[64 + t] + red[128 + t] + red[192 + t];
    } else if (bx < 784) {
        // Wf f32 -> bf16 (131072 float4 groups over 512 blocks)
        int i = (bx - 272) * 256 + t;
        float4 v = *reinterpret_cast<const float4*>(wf + (size_t)i * 4);
        ushort4 o = make_ushort4(f2bf(v.x), f2bf(v.y), f2bf(v.z), f2bf(v.w));
        *reinterpret_cast<ushort4*>(wfb + (size_t)i * 4) = o;
    } else {
        // zero stats (denom[2BT] | avgs[BT] | maxe[BT]) = 4*BT floats = 36864 float4
        int i = (bx - 784) * 256 + t;
        *reinterpret_cast<float4*>(stats + (size_t)i * 4) = make_float4(0.f, 0.f, 0.f, 0.f);
    }
}

// ---------------- merged layernorms, wave-per-row, lane-contiguous loads ----------------
__global__ __launch_bounds__(512, 4) void k_lnorm(const float* __restrict__ tf,
                                                  const float* __restrict__ g,
                                                  const float* __restrict__ bta,
                                                  const float* __restrict__ x,
                                                  unsigned short* __restrict__ kvn,
                                                  unsigned short* __restrict__ xn) {
    int bid = blockIdx.x;
    int l = threadIdx.x & 63;
    if (bid < 8192) {
        int trow = bid * 8 + (threadIdx.x >> 6);     // tf-order: n*64 + b
        int n = trow >> 6, b = trow & 63;
        unsigned short* dst = kvn + ((size_t)b * NTQ_ + n) * TXT_;
        if (n >= NT_) {
            *reinterpret_cast<ushort4*>(dst + l * 4) = make_ushort4(0, 0, 0, 0);
            *reinterpret_cast<ushort4*>(dst + 256 + l * 4) = make_ushort4(0, 0, 0, 0);
            return;
        }
        const float* src = tf + (size_t)trow * TXT_;
        float4 v0 = *reinterpret_cast<const float4*>(src + l * 4);
        float4 v1 = *reinterpret_cast<const float4*>(src + 256 + l * 4);
        float s  = v0.x + v0.y + v0.z + v0.w + v1.x + v1.y + v1.z + v1.w;
        float ss = v0.x * v0.x + v0.y * v0.y + v0.z * v0.z + v0.w * v0.w
                 + v1.x * v1.x + v1.y * v1.y + v1.z * v1.z + v1.w * v1.w;
#pragma unroll
        for (int d = 1; d < 64; d <<= 1) { s += __shfl_xor(s, d); ss += __shfl_xor(ss, d); }
        float m = s * (1.f / TXT_);
        float rs = rsqrtf(ss * (1.f / TXT_) - m * m + 1e-5f);
        float4 g0 = *reinterpret_cast<const float4*>(g + l * 4);
        float4 g1 = *reinterpret_cast<const float4*>(g + 256 + l * 4);
        float4 b0 = *reinterpret_cast<const float4*>(bta + l * 4);
        float4 b1 = *reinterpret_cast<const float4*>(bta + 256 + l * 4);
        ushort4 o0 = make_ushort4(f2bf((v0.x - m) * rs * g0.x + b0.x),
                                  f2bf((v0.y - m) * rs * g0.y + b0.y),
                                  f2bf((v0.z - m) * rs * g0.z + b0.z),
                                  f2bf((v0.w - m) * rs * g0.w + b0.w));
        ushort4 o1 = make_ushort4(f2bf((v1.x - m) * rs * g1.x + b1.x),
                                  f2bf((v1.y - m) * rs * g1.y + b1.y),
                                  f2bf((v1.z - m) * rs * g1.z + b1.z),
                                  f2bf((v1.w - m) * rs * g1.w + b1.w));
        *reinterpret_cast<ushort4*>(dst + l * 4) = o0;
        *reinterpret_cast<ushort4*>(dst + 256 + l * 4) = o1;
    } else {
        int gr = 64 + (bid - 8192) * 8 + (threadIdx.x >> 6);
        int b = gr & 63, tk = (gr >> 6) - 1;
        const float* src = x + (size_t)gr * DIM_;
        float4 v[4];
#pragma unroll
        for (int j = 0; j < 4; ++j) v[j] = *reinterpret_cast<const float4*>(src + j * 256 + l * 4);
        float s = 0.f, ss = 0.f;
#pragma unroll
        for (int j = 0; j < 4; ++j) {
            s += v[j].x + v[j].y + v[j].z + v[j].w;
            ss += v[j].x * v[j].x + v[j].y * v[j].y + v[j].z * v[j].z + v[j].w * v[j].w;
        }
#pragma unroll
        for (int d = 1; d < 64; d <<= 1) { s += __shfl_xor(s, d); ss += __shfl_xor(ss, d); }
        float m = s * (1.f / DIM_);
        float rs = rsqrtf(ss * (1.f / DIM_) - m * m + 1e-5f);
        unsigned short* dst = xn + ((size_t)b * TOK_ + tk) * DIM_;
#pragma unroll
        for (int j = 0; j < 4; ++j) {
            ushort4 o = make_ushort4(f2bf((v[j].x - m) * rs), f2bf((v[j].y - m) * rs),
                                     f2bf((v[j].z - m) * rs), f2bf((v[j].w - m) * rs));
            *reinterpret_cast<ushort4*>(dst + j * 256 + l * 4) = o;
        }
    }
}

// ---------------- kv transpose:  kvn [b][n][e] -> kvt [b][e][n_pad1024] ----------------
__global__ void k_kvt(const unsigned short* __restrict__ kvn, unsigned short* __restrict__ kvt) {
    __shared__ unsigned short tile[64][68];
    int bx = blockIdx.x;
    int b = bx >> 7, rem = bx & 127, et = rem >> 4, nt = rem & 15;
    int t = threadIdx.x;
#pragma unroll
    for (int i = 0; i < 4; ++i) {
        int idx4 = t + i * 256;
        int nl = idx4 >> 4, e4 = (idx4 & 15) * 4;
        int ng = nt * 64 + nl;
        ushort4 v = make_ushort4(0, 0, 0, 0);
        if (ng < NT_) v = *reinterpret_cast<const ushort4*>(kvn + ((size_t)b * NTQ_ + ng) * TXT_ + et * 64 + e4);
        tile[nl][e4 + 0] = v.x; tile[nl][e4 + 1] = v.y; tile[nl][e4 + 2] = v.z; tile[nl][e4 + 3] = v.w;
    }
    __syncthreads();
#pragma unroll
    for (int i = 0; i < 4; ++i) {
        int idx4 = t + i * 256;
        int el = idx4 >> 4, n4 = (idx4 & 15) * 4;
        ushort4 o = make_ushort4(tile[n4 + 0][el], tile[n4 + 1][el], tile[n4 + 2][el], tile[n4 + 3][el]);
        *reinterpret_cast<ushort4*>(kvt + ((size_t)b * TXT_ + et * 64 + el) * NTP_ + nt * 64 + n4) = o;
    }
}

// ---------------- 128x128xK bf16 GEMM mainloop, global_load_lds staging (m97 structure) ----------------
// A:[M][K], B:[N][K], both k-contiguous.
__device__ __forceinline__ void gemm_loop_gll(const unsigned short* __restrict__ A,
                                              const unsigned short* __restrict__ Bp,
                                              int K, unsigned short* a_lds, unsigned short* b_lds,
                                              int tid, f32x4 acc[4][4]) {
    const int l = tid & 63, w = tid >> 6;
    const int l16 = l & 15, lg = l >> 4;
    const int wm = w & 1, wn = w >> 1;
    const f32x4 fz = {0.f, 0.f, 0.f, 0.f};
#pragma unroll
    for (int mt = 0; mt < 4; ++mt)
#pragma unroll
        for (int nt = 0; nt < 4; ++nt) acc[mt][nt] = fz;
    const int lrow = l >> 3;
    const int k8g = (l & 7) ^ lrow;
    const int nk = K >> 6;
    for (int kt = 0; kt < nk; ++kt) {
#pragma unroll
        for (int i = 0; i < 4; ++i) {
            int row = i * 32 + w * 8 + lrow;
            gll16(A + (size_t)row * K + kt * 64 + k8g * 8, &a_lds[(i * 256 + w * 64) * 8]);
        }
#pragma unroll
        for (int i = 0; i < 4; ++i) {
            int row = i * 32 + w * 8 + lrow;
            gll16(Bp + (size_t)row * K + kt * 64 + k8g * 8, &b_lds[(i * 256 + w * 64) * 8]);
        }
        __syncthreads();
#pragma unroll
        for (int kk = 0; kk < 2; ++kk) {
            bf16x8 af[4], bff[4];
#pragma unroll
            for (int mt = 0; mt < 4; ++mt) {
                int row = wm * 64 + mt * 16 + l16;
                int gs = (kk * 4 + lg) ^ (row & 7);
                af[mt] = *reinterpret_cast<const bf16x8*>(a_lds + row * 64 + gs * 8);
            }
#pragma unroll
            for (int nt = 0; nt < 4; ++nt) {
                int row = wn * 64 + nt * 16 + l16;
                int gs = (kk * 4 + lg) ^ (row & 7);
                bff[nt] = *reinterpret_cast<const bf16x8*>(b_lds + row * 64 + gs * 8);
            }
#pragma unroll
            for (int mt = 0; mt < 4; ++mt)
#pragma unroll
                for (int nt = 0; nt < 4; ++nt)
                    acc[mt][nt] = mfma16(af[mt], bff[nt], acc[mt][nt]);
        }
        __syncthreads();
    }
}

// ---------------- 96x128xK variant (M-tile 96 keeps tiles inside one b: 576 = 6*96) ----------------
__device__ __forceinline__ void gemm_loop96(const unsigned short* __restrict__ A,
                                            const unsigned short* __restrict__ Bp,
                                            int K, unsigned short* a_lds, unsigned short* b_lds,
                                            int tid, f32x4 acc[3][4]) {
    const int l = tid & 63, w = tid >> 6;
    const int l16 = l & 15, lg = l >> 4;
    const int wm = w & 1, wn = w >> 1;
    const f32x4 fz = {0.f, 0.f, 0.f, 0.f};
#pragma unroll
    for (int mt = 0; mt < 3; ++mt)
#pragma unroll
        for (int nt = 0; nt < 4; ++nt) acc[mt][nt] = fz;
    const int lrow = l >> 3;
    const int k8g = (l & 7) ^ lrow;
    const int nk = K >> 6;
    for (int kt = 0; kt < nk; ++kt) {
#pragma unroll
        for (int i = 0; i < 3; ++i) {
            int row = i * 32 + w * 8 + lrow;
            gll16(A + (size_t)row * K + kt * 64 + k8g * 8, &a_lds[(i * 256 + w * 64) * 8]);
        }
#pragma unroll
        for (int i = 0; i < 4; ++i) {
            int row = i * 32 + w * 8 + lrow;
            gll16(Bp + (size_t)row * K + kt * 64 + k8g * 8, &b_lds[(i * 256 + w * 64) * 8]);
        }
        __syncthreads();
#pragma unroll
        for (int kk = 0; kk < 2; ++kk) {
            bf16x8 af[3], bff[4];
#pragma unroll
            for (int mt = 0; mt < 3; ++mt) {
                int row = wm * 48 + mt * 16 + l16;
                int gs = (kk * 4 + lg) ^ (row & 7);
                af[mt] = *reinterpret_cast<const bf16x8*>(a_lds + row * 64 + gs * 8);
            }
#pragma unroll
            for (int nt = 0; nt < 4; ++nt) {
                int row = wn * 64 + nt * 16 + l16;
                int gs = (kk * 4 + lg) ^ (row & 7);
                bff[nt] = *reinterpret_cast<const bf16x8*>(b_lds + row * 64 + gs * 8);
            }
#pragma unroll
            for (int mt = 0; mt < 3; ++mt)
#pragma unroll
                for (int nt = 0; nt < 4; ++nt)
                    acc[mt][nt] = mfma16(af[mt], bff[nt], acc[mt][nt]);
        }
        __syncthreads();
    }
}

// q GEMM:  q[br] = (xn @ (diag(g)Wq[br])^T + bias) * SCALE  -> bf16 (36864x512)
__global__ __launch_bounds__(256, 4) void k_qgemm(const unsigned short* __restrict__ xn,
                                                  const unsigned short* __restrict__ wqt,
                                                  const float* __restrict__ qbias,
                                                  unsigned short* __restrict__ qb) {
    int bid = blockIdx.x;                        // 2304 = 4bn x 288bm x 2br
    int vb = (bid & 7) * 288 + (bid >> 3);       // XCD-contiguous
    int bn = vb & 3;
    int t = vb >> 2;
    int br = (t >= 288) ? 1 : 0;
    int bm = t - br * 288;
    const unsigned short* A = xn + (size_t)bm * 128 * DIM_;
    const unsigned short* Bp = wqt + (size_t)br * 512 * 1024 + (size_t)bn * 128 * 1024;
    unsigned short* C = qb + (size_t)br * BT_ * TXT_;
    const float* bias = qbias + br * 512;
    __shared__ unsigned short a_lds[128 * 64];
    __shared__ unsigned short b_lds[128 * 64];
    f32x4 acc[4][4];
    gemm_loop_gll(A, Bp, DIM_, a_lds, b_lds, threadIdx.x, acc);
    const int l = threadIdx.x & 63, w = threadIdx.x >> 6;
    const int l16 = l & 15, lg = l >> 4, wm = w & 1, wn = w >> 1;
#pragma unroll
    for (int mt = 0; mt < 4; ++mt)
#pragma unroll
        for (int nt = 0; nt < 4; ++nt) {
            int col = bn * 128 + wn * 64 + nt * 16 + l16;
            float bv = bias[col];
#pragma unroll
            for (int r = 0; r < 4; ++r) {
                int row = bm * 128 + wm * 64 + mt * 16 + lg * 4 + r;
                C[(size_t)row * TXT_ + col] = f2bf((acc[mt][nt][r] + bv) * SCALE_);
            }
        }
}

// score GEMM: P = exp(q @ kvn^T) per branch, + row-sum atomics into denom
__global__ __launch_bounds__(256, 4) void k_score(const unsigned short* __restrict__ qbuf,
                                                  const unsigned short* __restrict__ kvn,
                                                  unsigned short* __restrict__ P,
                                                  float* __restrict__ denom, int br) {
    int bid = blockIdx.x;                        // 3072 = 64b x 6mt x 8nt
    int vb = (bid & 7) * 384 + (bid >> 3);
    int tile = vb % 48, b = vb / 48;
    int mt = tile >> 3, nt = tile & 7;
    const unsigned short* A = qbuf + ((size_t)br * BT_ + (size_t)b * TOK_ + mt * 96) * TXT_;
    const unsigned short* Bp = kvn + (size_t)b * NTQ_ * TXT_ + (size_t)nt * 128 * TXT_;
    __shared__ unsigned short a_lds[96 * 64];
    __shared__ unsigned short b_lds[128 * 64];
    f32x4 acc[3][4];
    gemm_loop96(A, Bp, TXT_, a_lds, b_lds, threadIdx.x, acc);
    const int l = threadIdx.x & 63, w = threadIdx.x >> 6;
    const int l16 = l & 15, lg = l >> 4, wm = w & 1, wn = w >> 1;
    float* dn = denom + (size_t)br * BT_;
#pragma unroll
    for (int mt2 = 0; mt2 < 3; ++mt2)
#pragma unroll
        for (int r = 0; r < 4; ++r) {
            int row = b * TOK_ + mt * 96 + wm * 48 + mt2 * 16 + lg * 4 + r;
            float s = 0.f;
#pragma unroll
            for (int nt2 = 0; nt2 < 4; ++nt2) {
                int col = nt * 128 + wn * 64 + nt2 * 16 + l16;
                float p = (col < NT_) ? __expf(acc[mt2][nt2][r]) : 0.f;
                s += p;
                P[(size_t)row * NTP_ + col] = f2bf(p);
            }
#pragma unroll
            for (int d = 1; d < 16; d <<= 1) s += __shfl_xor(s, d);
            if (l16 == 0) atomicAdd(&dn[row], s);
        }
}

// PV GEMM: O = (P @ kvt^T) / denom -> bf16; fused per-row sum (br0) / max (br1) atomics
__global__ __launch_bounds__(256, 4) void k_pv(const unsigned short* __restrict__ P,
                                               const unsigned short* __restrict__ kvt,
                                               const float* __restrict__ denom,
                                               unsigned short* __restrict__ ob,
                                               float* __restrict__ avgs,
                                               unsigned* __restrict__ maxe, int br) {
    int bid = blockIdx.x;                        // 1536 = 64b x 6mt x 4nt
    int vb = (bid & 7) * 192 + (bid >> 3);
    int tile = vb % 24, b = vb / 24;
    int mt = tile >> 2, nt = tile & 3;
    const unsigned short* A = P + ((size_t)b * TOK_ + mt * 96) * NTP_;
    const unsigned short* Bp = kvt + (size_t)b * TXT_ * NTP_ + (size_t)nt * 128 * NTP_;
    __shared__ unsigned short a_lds[96 * 64];
    __shared__ unsigned short b_lds[128 * 64];
    f32x4 acc[3][4];
    gemm_loop96(A, Bp, NTP_, a_lds, b_lds, threadIdx.x, acc);
    const int l = threadIdx.x & 63, w = threadIdx.x >> 6;
    const int l16 = l & 15, lg = l >> 4, wm = w & 1, wn = w >> 1;
    const float* dn = denom + (size_t)br * BT_;
#pragma unroll
    for (int mt2 = 0; mt2 < 3; ++mt2)
#pragma unroll
        for (int r = 0; r < 4; ++r) {
            int row = b * TOK_ + mt * 96 + wm * 48 + mt2 * 16 + lg * 4 + r;
            float inv = 1.f / dn[row];
            unsigned short* dst = ob + ((size_t)br * BT_ + row) * TXT_;
            float sum = 0.f, mx = -1e30f;
#pragma unroll
            for (int nt2 = 0; nt2 < 4; ++nt2) {
                int col = nt * 128 + wn * 64 + nt2 * 16 + l16;
                float o = acc[mt2][nt2][r] * inv;
                dst[col] = f2bf(o);
                sum += o;
                mx = fmaxf(mx, o);
            }
#pragma unroll
            for (int d = 1; d < 16; d <<= 1) {
                sum += __shfl_xor(sum, d);
                mx = fmaxf(mx, __shfl_xor(mx, d));
            }
            if (l16 == 0) {
                if (br == 0) atomicAdd(&avgs[row], sum);
                else         atomicMax(&maxe[row], encmax(mx));
            }
        }
}

// final GEMM: y = xse (36864x512) @ Wf^T (1024x512) -> fp32 scattered into out layout
__global__ __launch_bounds__(256, 4) void k_fgemm(const unsigned short* __restrict__ xse,
                                                  const unsigned short* __restrict__ wfb,
                                                  float* __restrict__ out) {
    int bid = blockIdx.x;                        // 2304 = 8bn x 288bm
    int vb = (bid & 7) * 288 + (bid >> 3);
    int bn = vb & 7, bm = vb >> 3;
    const unsigned short* A = xse + (size_t)bm * 128 * TXT_;
    const unsigned short* Bp = wfb + (size_t)bn * 128 * TXT_;
    __shared__ unsigned short a_lds[128 * 64];
    __shared__ unsigned short b_lds[128 * 64];
    f32x4 acc[4][4];
    gemm_loop_gll(A, Bp, TXT_, a_lds, b_lds, threadIdx.x, acc);
    const int l = threadIdx.x & 63, w = threadIdx.x >> 6;
    const int l16 = l & 15, lg = l >> 4, wm = w & 1, wn = w >> 1;
#pragma unroll
    for (int mt = 0; mt < 4; ++mt)
#pragma unroll
        for (int r = 0; r < 4; ++r) {
            int rowg = bm * 128 + wm * 64 + mt * 16 + lg * 4 + r;
            int b = rowg / TOK_, tk = rowg - b * TOK_;
            float* dst = out + ((size_t)(tk + 1) * B_ + b) * DIM_;
#pragma unroll
            for (int nt = 0; nt < 4; ++nt) {
                int col = bn * 128 + wn * 64 + nt * 16 + l16;
                dst[col] = acc[mt][nt][r];
            }
        }
}

// ---------------- x_se = o1*g1 + o2*g2 -> bf16, with gate conv fused (lane 0 per row) ----------------
__global__ void k_xse(const unsigned short* __restrict__ o1, const unsigned short* __restrict__ o2,
                      const float* __restrict__ avgs, const unsigned* __restrict__ maxe,
                      const float* __restrict__ cdw, unsigned short* __restrict__ xse) {
    int idx8 = blockIdx.x * 256 + threadIdx.x;    // < 36864*64
    int bt = idx8 >> 6, e8 = threadIdx.x & 63;
    float gg1 = 0.f, gg2 = 0.f;
    if (e8 == 0) {
        int b = bt / TOK_, hw = bt - b * TOK_, h = hw / H_, ww = hw - h * H_;
        float a1 = 0.f, a2 = 0.f;
#pragma unroll
        for (int ky = 0; ky < 3; ++ky)
#pragma unroll
            for (int kx = 0; kx < 3; ++kx) {
                int hh = h + ky - 1, wx = ww + kx - 1;
                if (hh >= 0 && hh < H_ && wx >= 0 && wx < H_) {
                    float wv = cdw[ky * 3 + kx];
                    int s = b * TOK_ + hh * H_ + wx;
                    a1 += wv * avgs[s] * (1.f / TXT_);
                    a2 += wv * decmax(maxe[s]);
                }
            }
        gg1 = 1.f / (1.f + __expf(-a1));
        gg2 = 1.f / (1.f + __expf(-a2));
    }
    gg1 = __shfl(gg1, 0);
    gg2 = __shfl(gg2, 0);
    float f1[8], f2[8];
    unpack8(*reinterpret_cast<const uint4*>(o1 + (size_t)bt * TXT_ + e8 * 8), f1);
    unpack8(*reinterpret_cast<const uint4*>(o2 + (size_t)bt * TXT_ + e8 * 8), f2);
    unsigned r[4];
#pragma unroll
    for (int j = 0; j < 4; ++j) {
        unsigned lo = f2bf(f1[2 * j] * gg1 + f2[2 * j] * gg2);
        unsigned hi = f2bf(f1[2 * j + 1] * gg1 + f2[2 * j + 1] * gg2);
        r[j] = lo | (hi << 16);
    }
    uint4 o = make_uint4(r[0], r[1], r[2], r[3]);
    *reinterpret_cast<uint4*>(xse + (size_t)bt * TXT_ + e8 * 8) = o;
}

// ---------------- launcher ----------------
extern "C" void kernel_launch(void* const* d_in, const int* in_sizes, int n_in,
                              void* d_out, int out_size, void* d_ws, size_t ws_size,
                              hipStream_t stream) {
    (void)in_sizes; (void)n_in; (void)out_size; (void)ws_size;
    const float* x    = (const float*)d_in[0];
    const float* tf   = (const float*)d_in[1];
    const float* lq1g = (const float*)d_in[2];
    const float* lq1b = (const float*)d_in[3];
    const float* lq2g = (const float*)d_in[4];
    const float* lq2b = (const float*)d_in[5];
    const float* lkvg = (const float*)d_in[6];
    const float* lkvb = (const float*)d_in[7];
    const float* wq1  = (const float*)d_in[8];
    const float* wq2  = (const float*)d_in[9];
    const float* cdw  = (const float*)d_in[10];
    const float* wf   = (const float*)d_in[11];
    float* out = (float*)d_out;

    char* ws = (char*)d_ws;
    size_t off = 0;
    auto carve = [&](size_t bytes) { char* p = ws + off; off += (bytes + 255) & ~(size_t)255; return p; };
    unsigned short* kvn  = (unsigned short*)carve((size_t)B_ * NTQ_ * TXT_ * 2);       // 67.1 MB
    unsigned short* kvt  = (unsigned short*)carve((size_t)B_ * TXT_ * NTP_ * 2);       // 67.1 MB
    unsigned short* wqt  = (unsigned short*)carve((size_t)2 * 512 * 1024 * 2);         // 2 MB
    unsigned short* wfb  = (unsigned short*)carve((size_t)1024 * 512 * 2);             // 1 MB
    float* qbias = (float*)carve((size_t)2 * 512 * 4);
    float* stats = (float*)carve((size_t)4 * BT_ * 4);                                 // denom[2BT] | avgs[BT] | maxe[BT]
    float* denom = stats;
    float* avgs  = stats + 2 * BT_;
    unsigned* maxe = (unsigned*)(stats + 3 * BT_);
    unsigned short* xn   = (unsigned short*)carve((size_t)BT_ * DIM_ * 2);             // 75.5 MB
    unsigned short* qbuf = (unsigned short*)carve((size_t)2 * BT_ * TXT_ * 2);         // 75.5 MB
    unsigned short* ob   = (unsigned short*)carve((size_t)2 * BT_ * TXT_ * 2);         // 75.5 MB
    unsigned short* Pm   = xn;     // P (36864x1024 bf16, per branch): xn dead after k_qgemm
    unsigned short* xse  = qbuf;   // safe: qbuf dead after last k_score

    // row 0 of output = x_cls
    hipMemcpyAsync(out, x, (size_t)B_ * DIM_ * sizeof(float), hipMemcpyDeviceToDevice, stream);

    k_prep<<<928, 256, 0, stream>>>(wq1, wq2, lq1g, lq2g, lq1b, lq2b, wf, wqt, qbias, wfb, stats);
    k_lnorm<<<12800, 512, 0, stream>>>(tf, lkvg, lkvb, x, kvn, xn);
    k_kvt<<<8192, 256, 0, stream>>>(kvn, kvt);
    k_qgemm<<<2304, 256, 0, stream>>>(xn, wqt, qbias, qbuf);
    // branch 0
    k_score<<<3072, 256, 0, stream>>>(qbuf, kvn, Pm, denom, 0);
    k_pv<<<1536, 256, 0, stream>>>(Pm, kvt, denom, ob, avgs, maxe, 0);
    // branch 1 (P buffer reused; stream-ordered)
    k_score<<<3072, 256, 0, stream>>>(qbuf, kvn, Pm, denom, 1);
    k_pv<<<1536, 256, 0, stream>>>(Pm, kvt, denom, ob, avgs, maxe, 1);
    k_xse<<<9216, 256, 0, stream>>>(ob, ob + (size_t)BT_ * TXT_, avgs, maxe, cdw, xse);
    k_fgemm<<<2304, 256, 0, stream>>>(xse, wfb, out);
}